// Round 17
// baseline (119.294 us; speedup 1.0000x reference)
//
#include <hip/hip_runtime.h>
#include <math.h>

// DotProductAttention B=64,S=1024,D=64 fp32, bf16-MFMA flash attention.
// Round 19: T15 cross-iteration pipeline. r18's setprio confirmed (+2us,
// total 116.5 best). All three confirmed wins are latency/arbitration
// levers (chain -6, locality -4, setprio -2) -> floor = per-iter serial
// chain QK->softmax->PV x imperfect overlap. Last untried catalog lever:
// break the chain ACROSS iterations. With the r13 dbuf (proven neutral),
// hoist QK(i+1) before softmax/PV(i): QK MFMAs (matrix pipe) are data-
// independent of softmax (VALU/TRANS) and PV (other accumulator) -> co-
// issue on separate pipes within one wave (m114; T15 attn +7-11% m214v36).
// Schedule/iter: barrier A (protect buf[nxt]'s old readers) -> stage(i+1)
// + load(i+2) -> lgkm barrier B -> QK(i+1) from buf[nxt] -> mask/softmax/
// PV(i) from buf[cur] -> swap. +16 VGPR (second sc array), est ~116 < 128
// cap of (256,4) -- r1 spill signature would be VGPR=128 + FETCH blowup.
// Kept: XCD-local decode (r16), setprio (r18), P-in-reg slot perm (r9),
// lane-local defer THR=8 + deferred l (r12), lgkm-only barriers (r8).

#define BATCH 64
#define SEQ   1024
#define DIM   64
#define BQ    64           // queries per block (4 waves x 16)
#define BC    64           // keys per iteration
#define NKT   (SEQ / BC)   // 16
#define LSTR  72           // LDS row stride in bf16 (144 B)
#define QSCALE 0.18033688011112442f   // 0.125 * log2(e)
#define MASKED -1.0e6f
#define THR    8.0f        // defer-rescale threshold (exp2 domain)
#define KVSZ   (BC * LSTR) // 4608 ushorts per K (or V) tile

typedef __attribute__((ext_vector_type(8))) short bf16x8;
typedef __attribute__((ext_vector_type(4))) float f32x4;

__device__ __forceinline__ uint pack2_trunc(float lo, float hi) {
    // [bf16(hi) : bf16(lo)] by byte-select (truncation) — one v_perm_b32
    return __builtin_amdgcn_perm(__float_as_uint(hi), __float_as_uint(lo), 0x07060302);
}
__device__ __forceinline__ ushort f2bf_rne(float x) {
    uint u = __float_as_uint(x);
    return (ushort)((u + 0x7fffu + ((u >> 16) & 1u)) >> 16);
}

__global__ __launch_bounds__(256, 4) void attn_lean_pipe(
    const float* __restrict__ q, const float* __restrict__ k,
    const float* __restrict__ v, const int* __restrict__ valid_lens,
    float* __restrict__ out)
{
    __shared__ ushort SB[2][2 * KVSZ];   // [buf][Ks | Vt]

    const int t    = threadIdx.x;
    const int wave = t >> 6;
    const int wl   = t & 63;
    const int QD   = wl >> 4;          // quad 0..3
    const int li   = wl & 15;          // lane-in-quad 0..15

    // ---- XCD-local + CU-balanced decode (r16, validated) ----
    const int g    = blockIdx.x;
    const int x    = g & 7;
    const int y    = g >> 3;
    const int r    = y & 31;
    const int s    = y >> 5;
    const int bb   = (r + 2 * s) & 7;
    const int b    = x + 8 * bb;
    const int qt   = (r >> 3) * 4 + s;
    const int q0   = qt * BQ;
    const int vl   = valid_lens[b];

    const size_t boff = (size_t)b * SEQ * DIM;

    // ---- Q fragments (B-operand), pre-scaled, in registers ----
    bf16x8 qb[2];
    {
        const float* qrow = q + boff + (size_t)(q0 + wave * 16 + li) * DIM + QD * 8;
        #pragma unroll
        for (int kc = 0; kc < 2; kc++) {
            float4 a = *(const float4*)(qrow + kc * 32);
            float4 c = *(const float4*)(qrow + kc * 32 + 4);
            union { bf16x8 v; ushort u[8]; } tmp;
            tmp.u[0] = f2bf_rne(a.x * QSCALE);
            tmp.u[1] = f2bf_rne(a.y * QSCALE);
            tmp.u[2] = f2bf_rne(a.z * QSCALE);
            tmp.u[3] = f2bf_rne(a.w * QSCALE);
            tmp.u[4] = f2bf_rne(c.x * QSCALE);
            tmp.u[5] = f2bf_rne(c.y * QSCALE);
            tmp.u[6] = f2bf_rne(c.z * QSCALE);
            tmp.u[7] = f2bf_rne(c.w * QSCALE);
            qb[kc] = tmp.v;
        }
    }

    const int it_max = (vl == 0) ? NKT : ((vl + BC - 1) >> 6);

    // ---- prefetch registers ----
    float4 kf[4];
    float  vf[2][8];

    // V slot permutation (r9): slot ko*8+j holds key kb+((j>>2)<<5)+(j&3),
    // kb = (ko>>2)*16 + (ko&3)*4
    auto load_tile = [&](int it) {
        const float4* kg = (const float4*)(k + boff + (size_t)it * BC * DIM);
        #pragma unroll
        for (int i = 0; i < 4; i++) kf[i] = kg[t + 256 * i];
        const float* vgf = v + boff + (size_t)it * BC * DIM;
        #pragma unroll
        for (int i = 0; i < 2; i++) {
            int slot = t + 256 * i;
            int d = slot & 63, ko = slot >> 6;
            int kb = (ko >> 2) * 16 + (ko & 3) * 4;
            #pragma unroll
            for (int j = 0; j < 8; j++) {
                int kk = kb + ((j >> 2) << 5) + (j & 3);
                vf[i][j] = vgf[(size_t)kk * DIM + d];
            }
        }
    };

    auto stage = [&](int buf) {
        ushort* Ksb = SB[buf];
        ushort* Vtb = SB[buf] + KVSZ;
        #pragma unroll
        for (int i = 0; i < 4; i++) {
            int idx = t + 256 * i;
            int row = idx >> 4, c4 = idx & 15;
            uint2 w;
            w.x = pack2_trunc(kf[i].x, kf[i].y);
            w.y = pack2_trunc(kf[i].z, kf[i].w);
            *(uint2*)&Ksb[row * LSTR + c4 * 4] = w;
        }
        #pragma unroll
        for (int i = 0; i < 2; i++) {
            int slot = t + 256 * i;
            int d = slot & 63, ko = slot >> 6;
            uint4 w;
            w.x = pack2_trunc(vf[i][0], vf[i][1]);
            w.y = pack2_trunc(vf[i][2], vf[i][3]);
            w.z = pack2_trunc(vf[i][4], vf[i][5]);
            w.w = pack2_trunc(vf[i][6], vf[i][7]);
            *(uint4*)&Vtb[d * LSTR + ko * 8] = w;
        }
    };

    auto qkt = [&](int buf, f32x4* sc) {
        const ushort* Ksb = SB[buf];
        #pragma unroll
        for (int kt = 0; kt < 4; kt++) {
            bf16x8 ka0 = *(const bf16x8*)&Ksb[(kt * 16 + li) * LSTR + QD * 8];
            bf16x8 ka1 = *(const bf16x8*)&Ksb[(kt * 16 + li) * LSTR + 32 + QD * 8];
            f32x4 c = (f32x4){0.f, 0.f, 0.f, 0.f};
            c = __builtin_amdgcn_mfma_f32_16x16x32_bf16(ka0, qb[0], c, 0, 0, 0);
            c = __builtin_amdgcn_mfma_f32_16x16x32_bf16(ka1, qb[1], c, 0, 0, 0);
            sc[kt] = c;
        }
    };

    float m_run = -INFINITY;
    float l_run = 0.f;                 // per-lane partial (reduced once at end)
    f32x4 acc[4];
    #pragma unroll
    for (int dt = 0; dt < 4; dt++) acc[dt] = (f32x4){0.f, 0.f, 0.f, 0.f};

    // softmax + PV for tile `it` whose scores are in sc, V in buf
    auto finish_tile = [&](int it, int buf, f32x4* sc) {
        const ushort* Vtb = SB[buf] + KVSZ;
        const int kbase = it * BC;
        if (kbase + BC > vl) {
            #pragma unroll
            for (int kt = 0; kt < 4; kt++)
                #pragma unroll
                for (int r2 = 0; r2 < 4; r2++) {
                    int key = kbase + kt * 16 + QD * 4 + r2;
                    if (key >= vl) sc[kt][r2] = MASKED;
                }
        }

        float mt = -INFINITY;                   // lane-local max (r12)
        #pragma unroll
        for (int kt = 0; kt < 4; kt++)
            #pragma unroll
            for (int r2 = 0; r2 < 4; r2++) mt = fmaxf(mt, sc[kt][r2]);

        if (!__all(mt - m_run <= THR)) {
            mt = fmaxf(mt, __shfl_xor(mt, 16, 64));
            mt = fmaxf(mt, __shfl_xor(mt, 32, 64));
            float mn = fmaxf(m_run, mt);
            float alpha = exp2f(m_run - mn);
            m_run = mn;
            l_run *= alpha;
            float a0 = __shfl(alpha, QD * 4 + 0, 64);
            float a1 = __shfl(alpha, QD * 4 + 1, 64);
            float a2 = __shfl(alpha, QD * 4 + 2, 64);
            float a3 = __shfl(alpha, QD * 4 + 3, 64);
            #pragma unroll
            for (int dt = 0; dt < 4; dt++) {
                acc[dt][0] *= a0; acc[dt][1] *= a1;
                acc[dt][2] *= a2; acc[dt][3] *= a3;
            }
        }

        union { bf16x8 v; uint u[4]; } pa0u, pa1u;
        {
            float p00 = exp2f(sc[0][0] - m_run), p01 = exp2f(sc[0][1] - m_run);
            float p02 = exp2f(sc[0][2] - m_run), p03 = exp2f(sc[0][3] - m_run);
            float p10 = exp2f(sc[1][0] - m_run), p11 = exp2f(sc[1][1] - m_run);
            float p12 = exp2f(sc[1][2] - m_run), p13 = exp2f(sc[1][3] - m_run);
            float p20 = exp2f(sc[2][0] - m_run), p21 = exp2f(sc[2][1] - m_run);
            float p22 = exp2f(sc[2][2] - m_run), p23 = exp2f(sc[2][3] - m_run);
            float p30 = exp2f(sc[3][0] - m_run), p31 = exp2f(sc[3][1] - m_run);
            float p32 = exp2f(sc[3][2] - m_run), p33 = exp2f(sc[3][3] - m_run);
            l_run += ((p00 + p01) + (p02 + p03)) + ((p10 + p11) + (p12 + p13))
                   + ((p20 + p21) + (p22 + p23)) + ((p30 + p31) + (p32 + p33));
            pa0u.u[0] = pack2_trunc(p00, p01);
            pa0u.u[1] = pack2_trunc(p02, p03);
            pa0u.u[2] = pack2_trunc(p20, p21);
            pa0u.u[3] = pack2_trunc(p22, p23);
            pa1u.u[0] = pack2_trunc(p10, p11);
            pa1u.u[1] = pack2_trunc(p12, p13);
            pa1u.u[2] = pack2_trunc(p30, p31);
            pa1u.u[3] = pack2_trunc(p32, p33);
        }

        #pragma unroll
        for (int dt = 0; dt < 4; dt++) {
            bf16x8 vb0 = *(const bf16x8*)&Vtb[(dt * 16 + li) * LSTR + QD * 8];
            bf16x8 vb1 = *(const bf16x8*)&Vtb[(dt * 16 + li) * LSTR + 32 + QD * 8];
            acc[dt] = __builtin_amdgcn_mfma_f32_16x16x32_bf16(pa0u.v, vb0, acc[dt], 0, 0, 0);
            acc[dt] = __builtin_amdgcn_mfma_f32_16x16x32_bf16(pa1u.v, vb1, acc[dt], 0, 0, 0);
        }
    };

    // ---- prologue: tile 0 -> buf 0, QK(0) ----
    f32x4 sc_prev[4], sc_next[4];
    load_tile(0);
    stage(0);
    __builtin_amdgcn_sched_barrier(0);
    asm volatile("s_waitcnt lgkmcnt(0)" ::: "memory");
    __builtin_amdgcn_s_barrier();
    __builtin_amdgcn_sched_barrier(0);
    if (it_max > 1) load_tile(1);
    qkt(0, sc_prev);

    int cur = 0;
    // ---- pipelined loop: stage/QK tile i+1, finish tile i ----
    for (int i = 0; i + 1 < it_max; i++) {
        const int nxt = cur ^ 1;

        // barrier A: all waves done with buf[nxt]'s previous contents
        // (PV of tile i-1 finished last iteration before this point)
        __builtin_amdgcn_sched_barrier(0);
        __builtin_amdgcn_s_barrier();
        __builtin_amdgcn_sched_barrier(0);

        stage(nxt);                              // tile i+1 regs -> buf[nxt]
        if (i + 2 < it_max) load_tile(i + 2);    // vmcnt floats across B

        __builtin_amdgcn_sched_barrier(0);
        asm volatile("s_waitcnt lgkmcnt(0)" ::: "memory");
        __builtin_amdgcn_s_barrier();            // B: buf[nxt] visible
        __builtin_amdgcn_sched_barrier(0);

        __builtin_amdgcn_s_setprio(1);
        qkt(nxt, sc_next);                       // MFMA, independent of below
        finish_tile(i, cur, sc_prev);            // VALU+MFMA, overlaps above
        __builtin_amdgcn_s_setprio(0);

        #pragma unroll
        for (int kt = 0; kt < 4; kt++) sc_prev[kt] = sc_next[kt];
        cur = nxt;
    }

    // ---- tail: finish last tile ----
    __builtin_amdgcn_s_setprio(1);
    finish_tile(it_max - 1, cur, sc_prev);
    __builtin_amdgcn_s_setprio(0);

    // ---- deferred l reduction (once) + epilogue ----
    l_run += __shfl_xor(l_run, 16, 64);
    l_run += __shfl_xor(l_run, 32, 64);
    float invl = 1.0f / l_run;
    float i0 = __shfl(invl, QD * 4 + 0, 64);
    float i1 = __shfl(invl, QD * 4 + 1, 64);
    float i2 = __shfl(invl, QD * 4 + 2, 64);
    float i3 = __shfl(invl, QD * 4 + 3, 64);
    float* ob = out + boff + (size_t)q0 * DIM;
    const int rbase = wave * 16 + QD * 4;
    #pragma unroll
    for (int dt = 0; dt < 4; dt++) {
        int col = dt * 16 + li;
        ob[(size_t)(rbase + 0) * DIM + col] = acc[dt][0] * i0;
        ob[(size_t)(rbase + 1) * DIM + col] = acc[dt][1] * i1;
        ob[(size_t)(rbase + 2) * DIM + col] = acc[dt][2] * i2;
        ob[(size_t)(rbase + 3) * DIM + col] = acc[dt][3] * i3;
    }
}

extern "C" void kernel_launch(void* const* d_in, const int* in_sizes, int n_in,
                              void* d_out, int out_size, void* d_ws, size_t ws_size,
                              hipStream_t stream) {
    const float* q = (const float*)d_in[0];
    const float* k = (const float*)d_in[1];
    const float* v = (const float*)d_in[2];
    const int* valid_lens = (const int*)d_in[3];
    float* out = (float*)d_out;

    dim3 grid(BATCH * (SEQ / BQ));   // 64 x 16 = 1024 blocks
    dim3 block(256);
    attn_lean_pipe<<<grid, block, 0, stream>>>(q, k, v, valid_lens, out);
}